// Round 6
// baseline (1975.430 us; speedup 1.0000x reference)
//
#include <hip/hip_runtime.h>
#include <math.h>

#define NB   64
#define SS   96
#define EE   300
#define DD   512
#define HH   256
#define SELD 128
#define CK   1280   // 5*H
#define MLPD 1024
#define NCLS 3
#define RB   97     // state rows per batch: 96 initial + 1 spare (freed-row recycling)

// ---------------- transpose W_sel1 [e][k] -> [e4][k] float4 (4 consecutive e rows at col k) ------
__global__ void k_trans_sel(const float* __restrict__ Ws, float* __restrict__ Ws4) {
    int e4 = blockIdx.x;            // 0..127
    int k = threadIdx.x;            // 0..127
    float4 v;
    v.x = Ws[(4 * e4 + 0) * SELD + k];
    v.y = Ws[(4 * e4 + 1) * SELD + k];
    v.z = Ws[(4 * e4 + 2) * SELD + k];
    v.w = Ws[(4 * e4 + 3) * SELD + k];
    ((float4*)Ws4)[e4 * SELD + k] = v;
}

// ---------------- init parity-0 bookkeeping ------------------------------------------------------
__global__ void k_init(int* __restrict__ acts, int* __restrict__ rec) {
    int b = blockIdx.x, tid = threadIdx.x;
    acts[b * SS + tid] = tid;                     // parity-0
    if (tid == 0) {
        int* r = rec + b * 4;                     // parity-0
        r[0] = 0; r[1] = 0; r[2] = 0; r[3] = SS;  // pidx, pv0, pv1, freerow
    }
}

// ---------------- encode v4: LDS x-tile, 8 cols x 8 sents per thread ----------------------------
__global__ __launch_bounds__(256) void k_encode(const int* __restrict__ sent,
                                                const float* __restrict__ emb,
                                                const float* __restrict__ Wenc,
                                                const float* __restrict__ benc,
                                                float* __restrict__ state) {
    int b = blockIdx.x / 3, tile = blockIdx.x % 3, s0 = tile * 32;
    __shared__ int tok[32];
    __shared__ __align__(16) float elds[32 * 300];
    int tid = threadIdx.x;
    if (tid < 32) tok[tid] = sent[b * SS + s0 + tid];
    __syncthreads();
    {   // stage x tile as float4 (75 f4 per row)
        const float4* e4p = (const float4*)emb;
        float4* l4 = (float4*)elds;
        for (int i4 = tid; i4 < 32 * 75; i4 += 256) {
            int s = i4 / 75, r = i4 - s * 75;
            l4[s * 75 + r] = e4p[(size_t)tok[s] * 75 + r];
        }
    }
    __syncthreads();
    int sq = tid >> 6, cg = tid & 63;             // s-base sq*8, col-base cg*8
    int sb = sq * 8, colb = cg * 8;
    float4 accA[8], accB[8];
    {
        float4 bA = *(const float4*)&benc[colb];
        float4 bB = *(const float4*)&benc[colb + 4];
#pragma unroll
        for (int s = 0; s < 8; s++) { accA[s] = bA; accB[s] = bB; }
    }
    const float4* l4 = (const float4*)elds;
    for (int e4 = 0; e4 < 75; e4++) {
        float4 wA[4], wB[4];
#pragma unroll
        for (int j = 0; j < 4; j++) {
            const float* wr = Wenc + (size_t)(4 * e4 + j) * DD + colb;
            wA[j] = *(const float4*)wr;
            wB[j] = *(const float4*)(wr + 4);
        }
#pragma unroll
        for (int s = 0; s < 8; s++) {
            float4 xv = l4[(sb + s) * 75 + e4];
            accA[s].x += xv.x * wA[0].x + xv.y * wA[1].x + xv.z * wA[2].x + xv.w * wA[3].x;
            accA[s].y += xv.x * wA[0].y + xv.y * wA[1].y + xv.z * wA[2].y + xv.w * wA[3].y;
            accA[s].z += xv.x * wA[0].z + xv.y * wA[1].z + xv.z * wA[2].z + xv.w * wA[3].z;
            accA[s].w += xv.x * wA[0].w + xv.y * wA[1].w + xv.z * wA[2].w + xv.w * wA[3].w;
            accB[s].x += xv.x * wB[0].x + xv.y * wB[1].x + xv.z * wB[2].x + xv.w * wB[3].x;
            accB[s].y += xv.x * wB[0].y + xv.y * wB[1].y + xv.z * wB[2].y + xv.w * wB[3].y;
            accB[s].z += xv.x * wB[0].z + xv.y * wB[1].z + xv.z * wB[2].z + xv.w * wB[3].z;
            accB[s].w += xv.x * wB[0].w + xv.y * wB[1].w + xv.z * wB[2].w + xv.w * wB[3].w;
        }
    }
#pragma unroll
    for (int s = 0; s < 8; s++) {
        float* dst = state + ((size_t)b * RB + s0 + sb + s) * DD + colb;
        *(float4*)dst = accA[s];
        *(float4*)(dst + 4) = accB[s];
    }
}

// ---------------- initial logits for all 95 pairs per batch (parity-0) ---------------------------
__global__ __launch_bounds__(128) void k_logits0(const float* __restrict__ state,
                                                 const float* __restrict__ Ws4,
                                                 const float* __restrict__ bs1,
                                                 const float* __restrict__ Ws2,
                                                 const float* __restrict__ bs2,
                                                 float* __restrict__ logits) {
    int b = blockIdx.x / 5, tile = blockIdx.x % 5, p0 = tile * 19;
    __shared__ __align__(16) float hl[20 * 256];
    __shared__ float part[2][19];
    int tid = threadIdx.x;
    for (int i = tid; i < 20 * 256; i += 128) {
        int r = i >> 8, c = i & 255;
        hl[i] = state[((size_t)b * RB + p0 + r) * DD + HH + c];
    }
    __syncthreads();
    int k = tid;
    float acc[19];
#pragma unroll
    for (int p = 0; p < 19; p++) acc[p] = 0.f;
    const float4* W4 = (const float4*)Ws4;
    const float4* h4 = (const float4*)hl;
    for (int e4 = 0; e4 < 128; e4++) {
        float4 w = W4[e4 * SELD + k];
#pragma unroll
        for (int p = 0; p < 19; p++) {
            float4 x = h4[p * 64 + e4];
            acc[p] += x.x * w.x + x.y * w.y + x.z * w.z + x.w * w.w;
        }
    }
    float b1 = bs1[k], w2 = Ws2[k];
    int wid = tid >> 6, lane = tid & 63;
#pragma unroll
    for (int p = 0; p < 19; p++) {
        float y = tanhf(acc[p] + b1) * w2;
        for (int off = 32; off >= 1; off >>= 1) y += __shfl_down(y, off);
        if (lane == 0) part[wid][p] = y;
    }
    __syncthreads();
    if (tid < 19) logits[b * SS + p0 + tid] = part[0][tid] + part[1][tid] + bs2[0];
}

// ---------------- fused step kernel v3: 256 blocks = 16 batch-groups x 16 unit-tiles -------------
// PselT layout: [parity][b][pair][k(128)][u2(16)] floats.
__global__ __launch_bounds__(320) void k_step(const float* __restrict__ Wc,
                                              const float* __restrict__ bcomp,
                                              const float* __restrict__ Ws4,
                                              const float* __restrict__ bs1,
                                              const float* __restrict__ Ws2,
                                              const float* __restrict__ bs2,
                                              float* __restrict__ logits,
                                              int* __restrict__ acts,
                                              int* __restrict__ rec,
                                              int* __restrict__ nlUsed,
                                              float* __restrict__ PselT,
                                              float* __restrict__ state, int t) {
    int bg = blockIdx.x & 15, ut = blockIdx.x >> 4;
    int tid = threadIdx.x, w = tid >> 6, lane = tid & 63;
    int n = SS - t, p = t & 1, np = p ^ 1;

    __shared__ float lgl[4][SS];
    __shared__ int   acl[4][SS];
    __shared__ int   recl[4][8];                 // idx,l,r,nl,lm1,r2,v0,v1
    __shared__ int   rro[4][4];                  // rec raw
    __shared__ float L01[4][2];
    __shared__ __align__(16) float4 xst[4][128]; // [h_l | h_r] per batch
    __shared__ float cl[4][16], cr[4][16], lm1s[4][16], r2s[4][16], hn[4][16];
    __shared__ __align__(16) float4 sp4[4][4][20]; // [b][ks][colquad]
    __shared__ float ppex[4][2][2][SELD];        // [b][pair][half][k]

    // ---- phase A+B: all independent global loads issued together; L01 partial-sum finish ----
    if (tid < 16) rro[tid >> 2][tid & 3] = rec[((size_t)p * NB + bg * 4 + (tid >> 2)) * 4 + (tid & 3)];
    float x0v = -3.0e38f, x1v = -3.0e38f;
    if (tid < 256) {
        int b = bg * 4 + w;
        const float* lgp = logits + ((size_t)p * NB + b) * SS;
        const int* acp = acts + ((size_t)p * NB + b) * SS;
        int j0 = lane, j1 = lane + 64;
        if (j0 <= n - 2) x0v = lgp[j0];
        if (j1 <= n - 2) x1v = lgp[j1];
        acl[w][j0] = acp[j0];
        if (j1 < SS) acl[w][j1] = acp[j1];
        if (t > 0) {
            const float4* Pb = (const float4*)(PselT + ((size_t)(p * NB + b) * 2) * 2048);
            float s00 = bs1[lane], s01 = bs1[lane + 64];
            float s10 = s00, s11 = s01;
#pragma unroll
            for (int ch = 0; ch < 4; ch++) {
                float4 v00 = Pb[(lane) * 4 + ch];
                float4 v01 = Pb[(lane + 64) * 4 + ch];
                float4 v10 = Pb[(128 + lane) * 4 + ch];
                float4 v11 = Pb[(128 + lane + 64) * 4 + ch];
                s00 += v00.x + v00.y + v00.z + v00.w;
                s01 += v01.x + v01.y + v01.z + v01.w;
                s10 += v10.x + v10.y + v10.z + v10.w;
                s11 += v11.x + v11.y + v11.z + v11.w;
            }
            float yA = tanhf(s00) * Ws2[lane] + tanhf(s01) * Ws2[lane + 64];
            float yB = tanhf(s10) * Ws2[lane] + tanhf(s11) * Ws2[lane + 64];
#pragma unroll
            for (int off = 1; off < 64; off <<= 1) {
                yA += __shfl_xor(yA, off);
                yB += __shfl_xor(yB, off);
            }
            if (lane == 0) { L01[w][0] = yA + bs2[0]; L01[w][1] = yB + bs2[0]; }
        }
    }
    __syncthreads();

    // ---- phase C: patch + argmax (numpy first-max) ----
    if (tid < 256) {
        int pidx = rro[w][0], pv0 = rro[w][1], pv1 = rro[w][2];
        int j0 = lane, j1 = lane + 64;
        if (t > 0) {
            if (pv0) { if (j0 == pidx - 1) x0v = L01[w][0]; if (j1 == pidx - 1) x1v = L01[w][0]; }
            if (pv1) { if (j0 == pidx)     x0v = L01[w][1]; if (j1 == pidx)     x1v = L01[w][1]; }
        }
        if (j0 <= n - 2) lgl[w][j0] = x0v;
        if (j1 <= n - 2) lgl[w][j1] = x1v;
        float v = x0v; int i = j0;
        if (x1v > v) { v = x1v; i = j1; }
#pragma unroll
        for (int off = 1; off < 64; off <<= 1) {
            float ov = __shfl_xor(v, off);
            int oi = __shfl_xor(i, off);
            if (ov > v || (ov == v && oi < i)) { v = ov; i = oi; }
        }
        if (lane == 0) {
            int idx = i, l = acl[w][idx], r = acl[w][idx + 1];
            int v0 = (idx >= 1), v1 = (idx <= n - 3);
            recl[w][0] = idx; recl[w][1] = l; recl[w][2] = r; recl[w][3] = rro[w][3];
            recl[w][4] = v0 ? acl[w][idx - 1] : 0;
            recl[w][5] = v1 ? acl[w][idx + 2] : 0;
            recl[w][6] = v0; recl[w][7] = v1;
        }
    }
    __syncthreads();

    // ---- phase D: stage x rows + unit slices; bookkeeping (ut==0) overlapped ----
    for (int i = tid; i < 512; i += 320) {
        int b = i >> 7, j4 = i & 127;
        int row = (j4 < 64) ? recl[b][1] : recl[b][2];
        xst[b][j4] = ((const float4*)(state + ((size_t)(bg * 4 + b) * RB + row) * DD + HH))[j4 & 63];
    }
    if (tid < 256) {
        int which = tid >> 6, b2 = (tid >> 4) & 3, u = tid & 15;
        const float* sb = state + (size_t)(bg * 4 + b2) * RB * DD;
        if (which == 0)      cl[b2][u]   = sb[(size_t)recl[b2][1] * DD + ut * 16 + u];
        else if (which == 1) cr[b2][u]   = sb[(size_t)recl[b2][2] * DD + ut * 16 + u];
        else if (which == 2) lm1s[b2][u] = sb[(size_t)recl[b2][4] * DD + HH + ut * 16 + u];
        else                 r2s[b2][u]  = sb[(size_t)recl[b2][5] * DD + HH + ut * 16 + u];
    }
    if (ut == 0 && tid < 256) {
        int b = bg * 4 + w;
        int idx = recl[w][0], l = recl[w][1], nl = recl[w][3];
        int* acn = acts + ((size_t)np * NB + b) * SS;
        float* lgn = logits + ((size_t)np * NB + b) * SS;
        for (int j = lane; j <= n - 2; j += 64)
            acn[j] = (j < idx) ? acl[w][j] : ((j == idx) ? nl : acl[w][j + 1]);
        for (int j = lane; j <= n - 3; j += 64)
            if (j != idx - 1 && j != idx)
                lgn[j] = (j < idx - 1) ? lgl[w][j] : lgl[w][j + 1];
        if (lane == 0) {
            int* rn = rec + ((size_t)np * NB + b) * 4;
            rn[0] = idx; rn[1] = recl[w][6]; rn[2] = recl[w][7]; rn[3] = l;
            nlUsed[b] = nl;
        }
    }
    __syncthreads();

    // ---- phase E: compose matvec; thread = (b:4, ks:4, cq:20); native-layout f4 W loads ----
    {
        int b = tid / 80, rem = tid % 80, ks = rem / 20, cq = rem % 20;
        int g = cq >> 2, q = cq & 3;                 // col quad: g*256 + ut*16 + q*4
        int colb = g * 256 + ut * 16 + q * 4;
        const float4* x4 = &xst[b][0];
        float4 acc = make_float4(0.f, 0.f, 0.f, 0.f);
        const float* wb = Wc + (size_t)(ks * 128) * CK + colb;
#pragma unroll 4
        for (int e4 = 0; e4 < 32; e4++) {
            float4 xv = x4[ks * 32 + e4];
            float4 w0 = *(const float4*)(wb);
            float4 w1 = *(const float4*)(wb + CK);
            float4 w2v = *(const float4*)(wb + 2 * CK);
            float4 w3v = *(const float4*)(wb + 3 * CK);
            acc.x += xv.x * w0.x + xv.y * w1.x + xv.z * w2v.x + xv.w * w3v.x;
            acc.y += xv.x * w0.y + xv.y * w1.y + xv.z * w2v.y + xv.w * w3v.y;
            acc.z += xv.x * w0.z + xv.y * w1.z + xv.z * w2v.z + xv.w * w3v.z;
            acc.w += xv.x * w0.w + xv.y * w1.w + xv.z * w2v.w + xv.w * w3v.w;
            wb += 4 * CK;
        }
        sp4[b][ks][cq] = acc;
    }
    __syncthreads();

    // ---- reduce K-partials + gates fused; write composed c,h into fresh row ----
    if (tid < 64) {
        int b = tid >> 4, u = tid & 15;
        float a[5];
#pragma unroll
        for (int g = 0; g < 5; g++) {
            int j = g * 16 + u, q = j >> 2, e = j & 3;
            const float* s0 = (const float*)&sp4[b][0][q];
            const float* s1 = (const float*)&sp4[b][1][q];
            const float* s2 = (const float*)&sp4[b][2][q];
            const float* s3 = (const float*)&sp4[b][3][q];
            a[g] = s0[e] + s1[e] + s2[e] + s3[e] + bcomp[g * 256 + ut * 16 + u];
        }
        float si  = 1.f / (1.f + expf(-a[0]));
        float sfl = 1.f / (1.f + expf(-a[1]));
        float sfr = 1.f / (1.f + expf(-a[2]));
        float so  = 1.f / (1.f + expf(-a[3]));
        float cv = sfl * cl[b][u] + sfr * cr[b][u] + si * tanhf(a[4]);
        float hv = so * tanhf(cv);
        float* sb = state + (size_t)(bg * 4 + b) * RB * DD;
        int nl = recl[b][3];
        sb[(size_t)nl * DD + ut * 16 + u] = cv;
        sb[(size_t)nl * DD + HH + ut * 16 + u] = hv;
        hn[b][u] = hv;
    }
    __syncthreads();

    // ---- phase G: sel partials for next step's 2 refreshed pairs (own 32 x-dims) ----
    if (tid < 256) {
        int kk = tid & 127, half = tid >> 7;
        int e4base = half * 64 + ut * 4;
        const float4* W4 = (const float4*)Ws4;
        float P0[4] = {0.f, 0.f, 0.f, 0.f}, P1[4] = {0.f, 0.f, 0.f, 0.f};
#pragma unroll
        for (int j = 0; j < 4; j++) {
            float4 wv = W4[(size_t)(e4base + j) * SELD + kk];
#pragma unroll
            for (int b4 = 0; b4 < 4; b4++) {
                const float* xa0 = half ? hn[b4] : lm1s[b4];   // pair0: [h_lm1 | h_new]
                const float* xa1 = half ? r2s[b4] : hn[b4];    // pair1: [h_new | h_r2]
                P0[b4] += wv.x * xa0[4 * j] + wv.y * xa0[4 * j + 1]
                        + wv.z * xa0[4 * j + 2] + wv.w * xa0[4 * j + 3];
                P1[b4] += wv.x * xa1[4 * j] + wv.y * xa1[4 * j + 1]
                        + wv.z * xa1[4 * j + 2] + wv.w * xa1[4 * j + 3];
            }
        }
#pragma unroll
        for (int b4 = 0; b4 < 4; b4++) {
            ppex[b4][0][half][kk] = P0[b4];
            ppex[b4][1][half][kk] = P1[b4];
        }
    }
    __syncthreads();
    if (tid < 256) {
        int kk = tid & 127, pr = tid >> 7;
#pragma unroll
        for (int b4 = 0; b4 < 4; b4++) {
            int b = bg * 4 + b4;
            PselT[((size_t)(np * NB + b) * 2 + pr) * 2048 + kk * 16 + ut] =
                ppex[b4][pr][0][kk] + ppex[b4][pr][1][kk];
        }
    }
}

// ---------------- MLP head, column-parallel ------------------------------------------------------
__global__ __launch_bounds__(256) void k_mlp1(const float* __restrict__ state,
                                              const int* __restrict__ nlUsed,
                                              const float* __restrict__ Wm1,
                                              const float* __restrict__ bm1,
                                              float* __restrict__ x1g) {
    int b = blockIdx.x >> 2, q = blockIdx.x & 3, tid = threadIdx.x;
    int col = q * 256 + tid;
    __shared__ float x0[HH];
    int root = nlUsed[b];
    x0[tid] = state[((size_t)b * RB + root) * DD + HH + tid];
    __syncthreads();
    float acc = bm1[col];
    for (int e = 0; e < HH; e++) acc += x0[e] * Wm1[(size_t)e * MLPD + col];
    x1g[(size_t)b * MLPD + col] = fmaxf(acc, 0.f);
}

__global__ __launch_bounds__(128) void k_mlp2(const float* __restrict__ x1g,
                                              const float* __restrict__ Wm2,
                                              const float* __restrict__ bm2,
                                              float* __restrict__ x2g) {
    int b = blockIdx.x >> 3, q = blockIdx.x & 7, tid = threadIdx.x;
    int col = q * 128 + tid;
    __shared__ __align__(16) float x1[MLPD];
    for (int i = tid; i < 256; i += 128)
        ((float4*)x1)[i] = ((const float4*)(x1g + (size_t)b * MLPD))[i];
    __syncthreads();
    float acc = bm2[col];
    for (int e = 0; e < MLPD; e++) acc += x1[e] * Wm2[(size_t)e * MLPD + col];
    x2g[(size_t)b * MLPD + col] = fmaxf(acc, 0.f);
}

__global__ __launch_bounds__(256) void k_mlp3(const float* __restrict__ x2g,
                                              const float* __restrict__ Wout,
                                              const float* __restrict__ bout,
                                              float* __restrict__ out) {
    int b = blockIdx.x, tid = threadIdx.x;
    __shared__ __align__(16) float x2[MLPD];
    __shared__ float red3[3][256];
    ((float4*)x2)[tid] = ((const float4*)(x2g + (size_t)b * MLPD))[tid];
    __syncthreads();
    float p0 = 0.f, p1 = 0.f, p2 = 0.f;
    for (int e = tid; e < MLPD; e += 256) {
        float x = x2[e];
        p0 += x * Wout[e * NCLS + 0];
        p1 += x * Wout[e * NCLS + 1];
        p2 += x * Wout[e * NCLS + 2];
    }
    red3[0][tid] = p0; red3[1][tid] = p1; red3[2][tid] = p2;
    __syncthreads();
    for (int sdd = 128; sdd >= 1; sdd >>= 1) {
        if (tid < sdd) {
            red3[0][tid] += red3[0][tid + sdd];
            red3[1][tid] += red3[1][tid + sdd];
            red3[2][tid] += red3[2][tid + sdd];
        }
        __syncthreads();
    }
    if (tid < NCLS) out[b * NCLS + tid] = red3[tid][0] + bout[tid];
}

extern "C" void kernel_launch(void* const* d_in, const int* in_sizes, int n_in,
                              void* d_out, int out_size, void* d_ws, size_t ws_size,
                              hipStream_t stream) {
    const int*   sent  = (const int*)d_in[0];
    // d_in[1] = transitions: unused by the reference
    const float* emb   = (const float*)d_in[2];
    const float* Wenc  = (const float*)d_in[3];
    const float* benc  = (const float*)d_in[4];
    const float* Wcomp = (const float*)d_in[5];
    const float* bcomp = (const float*)d_in[6];
    const float* Wsel1 = (const float*)d_in[7];
    const float* bs1   = (const float*)d_in[8];
    const float* Ws2   = (const float*)d_in[9];
    const float* bs2   = (const float*)d_in[10];
    const float* Wm1   = (const float*)d_in[11];
    const float* bm1   = (const float*)d_in[12];
    const float* Wm2   = (const float*)d_in[13];
    const float* bm2   = (const float*)d_in[14];
    const float* Wout  = (const float*)d_in[15];
    const float* bout  = (const float*)d_in[16];
    float* out = (float*)d_out;

    float* ws     = (float*)d_ws;
    float* state  = ws;                              // 3,178,496 f32
    float* Ws14   = ws + 3178496;                    // 65,536
    float* logits = ws + 3244032;                    // 2*64*96 = 12,288 (ping-pong)
    int*   acts   = (int*)(ws + 3256320);            // 12,288 ints (ping-pong)
    int*   rec    = (int*)(ws + 3268608);            // 512 ints (ping-pong)
    int*   nlUsed = (int*)(ws + 3269120);            // 64 ints
    float* PselT  = ws + 3269184;                    // 2*64*2*128*16 = 524,288 (ping-pong)
    float* x1g    = ws + 3269184;                    // alias: PselT dead after scan
    float* x2g    = ws + 3334720;                    // alias

    k_trans_sel<<<dim3(128), dim3(128), 0, stream>>>(Wsel1, Ws14);
    k_init<<<dim3(NB), dim3(SS), 0, stream>>>(acts, rec);
    k_encode<<<dim3(NB * 3), dim3(256), 0, stream>>>(sent, emb, Wenc, benc, state);
    k_logits0<<<dim3(NB * 5), dim3(128), 0, stream>>>(state, Ws14, bs1, Ws2, bs2, logits);

    for (int t = 0; t < SS - 1; t++)   // t = 0..94
        k_step<<<dim3(256), dim3(320), 0, stream>>>(Wcomp, bcomp, Ws14, bs1, Ws2, bs2,
                                                    logits, acts, rec, nlUsed, PselT, state, t);

    k_mlp1<<<dim3(NB * 4), dim3(256), 0, stream>>>(state, nlUsed, Wm1, bm1, x1g);
    k_mlp2<<<dim3(NB * 8), dim3(128), 0, stream>>>(x1g, Wm2, bm2, x2g);
    k_mlp3<<<dim3(NB), dim3(256), 0, stream>>>(x2g, Wout, bout, out);
}

// Round 7
// 1380.437 us; speedup vs baseline: 1.4310x; 1.4310x over previous
//
#include <hip/hip_runtime.h>
#include <math.h>

#define NB   64
#define SS   96
#define EE   300
#define DD   512
#define HH   256
#define SELD 128
#define CK   1280   // 5*H
#define MLPD 1024
#define NCLS 3
#define RB   97     // state rows per batch: 96 initial + 1 spare (freed-row recycling)

// ---------------- transpose W_sel1 [e][k] -> [e4][k] float4 (4 consecutive e rows at col k) ------
__global__ void k_trans_sel(const float* __restrict__ Ws, float* __restrict__ Ws4) {
    int e4 = blockIdx.x;            // 0..127
    int k = threadIdx.x;            // 0..127
    float4 v;
    v.x = Ws[(4 * e4 + 0) * SELD + k];
    v.y = Ws[(4 * e4 + 1) * SELD + k];
    v.z = Ws[(4 * e4 + 2) * SELD + k];
    v.w = Ws[(4 * e4 + 3) * SELD + k];
    ((float4*)Ws4)[e4 * SELD + k] = v;
}

// ---------------- init parity-0 bookkeeping ------------------------------------------------------
__global__ void k_init(int* __restrict__ acts, int* __restrict__ rec) {
    int b = blockIdx.x, tid = threadIdx.x;
    acts[b * SS + tid] = tid;                     // parity-0
    if (tid == 0) {
        int* r = rec + b * 4;                     // parity-0
        r[0] = 0; r[1] = 0; r[2] = 0; r[3] = SS;  // pidx, pv0, pv1, freerow
    }
}

// ---------------- encode v5: 384 blocks (b x 3 s-tiles x 2 col-halves), 4 s x 8 cols/thread -----
__global__ __launch_bounds__(256) void k_encode(const int* __restrict__ sent,
                                                const float* __restrict__ emb,
                                                const float* __restrict__ Wenc,
                                                const float* __restrict__ benc,
                                                float* __restrict__ state) {
    int bi = blockIdx.x;
    int b = bi / 6, rem = bi % 6, tile = rem >> 1, ch = rem & 1;
    int s0 = tile * 32, col0 = ch * 256;
    __shared__ int tok[32];
    __shared__ __align__(16) float elds[32 * 300];
    int tid = threadIdx.x;
    if (tid < 32) tok[tid] = sent[b * SS + s0 + tid];
    __syncthreads();
    {
        const float4* e4p = (const float4*)emb;
        float4* l4s = (float4*)elds;
        for (int i4 = tid; i4 < 32 * 75; i4 += 256) {
            int s = i4 / 75, r = i4 - s * 75;
            l4s[i4] = e4p[(size_t)tok[s] * 75 + r];
        }
    }
    __syncthreads();
    int cg = tid & 31, sg = tid >> 5;            // lanes -> consecutive col-octets
    int colb = col0 + cg * 8, sb = sg * 4;
    float4 aA[4], aB[4];
    {
        float4 bA = *(const float4*)&benc[colb];
        float4 bB = *(const float4*)&benc[colb + 4];
#pragma unroll
        for (int s = 0; s < 4; s++) { aA[s] = bA; aB[s] = bB; }
    }
    const float4* l4 = (const float4*)elds;
    for (int e4 = 0; e4 < 75; e4++) {
        float4 wA[4], wB[4];
#pragma unroll
        for (int j = 0; j < 4; j++) {
            const float* wr = Wenc + (size_t)(4 * e4 + j) * DD + colb;
            wA[j] = *(const float4*)wr;
            wB[j] = *(const float4*)(wr + 4);
        }
#pragma unroll
        for (int s = 0; s < 4; s++) {
            float4 xv = l4[(sb + s) * 75 + e4];
            aA[s].x += xv.x * wA[0].x + xv.y * wA[1].x + xv.z * wA[2].x + xv.w * wA[3].x;
            aA[s].y += xv.x * wA[0].y + xv.y * wA[1].y + xv.z * wA[2].y + xv.w * wA[3].y;
            aA[s].z += xv.x * wA[0].z + xv.y * wA[1].z + xv.z * wA[2].z + xv.w * wA[3].z;
            aA[s].w += xv.x * wA[0].w + xv.y * wA[1].w + xv.z * wA[2].w + xv.w * wA[3].w;
            aB[s].x += xv.x * wB[0].x + xv.y * wB[1].x + xv.z * wB[2].x + xv.w * wB[3].x;
            aB[s].y += xv.x * wB[0].y + xv.y * wB[1].y + xv.z * wB[2].y + xv.w * wB[3].y;
            aB[s].z += xv.x * wB[0].z + xv.y * wB[1].z + xv.z * wB[2].z + xv.w * wB[3].z;
            aB[s].w += xv.x * wB[0].w + xv.y * wB[1].w + xv.z * wB[2].w + xv.w * wB[3].w;
        }
    }
#pragma unroll
    for (int s = 0; s < 4; s++) {
        float* dst = state + ((size_t)b * RB + s0 + sb + s) * DD + colb;
        *(float4*)dst = aA[s];
        *(float4*)(dst + 4) = aB[s];
    }
}

// ---------------- initial logits for all 95 pairs per batch (parity-0) ---------------------------
__global__ __launch_bounds__(128) void k_logits0(const float* __restrict__ state,
                                                 const float* __restrict__ Ws4,
                                                 const float* __restrict__ bs1,
                                                 const float* __restrict__ Ws2,
                                                 const float* __restrict__ bs2,
                                                 float* __restrict__ logits) {
    int b = blockIdx.x / 5, tile = blockIdx.x % 5, p0 = tile * 19;
    __shared__ __align__(16) float hl[20 * 256];
    __shared__ float part[2][19];
    int tid = threadIdx.x;
    for (int i = tid; i < 20 * 256; i += 128) {
        int r = i >> 8, c = i & 255;
        hl[i] = state[((size_t)b * RB + p0 + r) * DD + HH + c];
    }
    __syncthreads();
    int k = tid;
    float acc[19];
#pragma unroll
    for (int p = 0; p < 19; p++) acc[p] = 0.f;
    const float4* W4 = (const float4*)Ws4;
    const float4* h4 = (const float4*)hl;
    for (int e4 = 0; e4 < 128; e4++) {
        float4 w = W4[e4 * SELD + k];
#pragma unroll
        for (int p = 0; p < 19; p++) {
            float4 x = h4[p * 64 + e4];
            acc[p] += x.x * w.x + x.y * w.y + x.z * w.z + x.w * w.w;
        }
    }
    float b1 = bs1[k], w2 = Ws2[k];
    int wid = tid >> 6, lane = tid & 63;
#pragma unroll
    for (int p = 0; p < 19; p++) {
        float y = tanhf(acc[p] + b1) * w2;
        for (int off = 32; off >= 1; off >>= 1) y += __shfl_down(y, off);
        if (lane == 0) part[wid][p] = y;
    }
    __syncthreads();
    if (tid < 19) logits[b * SS + p0 + tid] = part[0][tid] + part[1][tid] + bs2[0];
}

// ---------------- fused step kernel v4: 256 blocks = 16 bg x 16 ut; 640 threads (10 waves) -------
// Matvec thread = (b-pair:2, ks:16, colquad:20); 2 batches amortized in regs per W float4.
__global__ __launch_bounds__(640) void k_step(const float* __restrict__ Wc,
                                              const float* __restrict__ bcomp,
                                              const float* __restrict__ Ws4,
                                              const float* __restrict__ bs1,
                                              const float* __restrict__ Ws2,
                                              const float* __restrict__ bs2,
                                              float* __restrict__ logits,
                                              int* __restrict__ acts,
                                              int* __restrict__ rec,
                                              int* __restrict__ nlUsed,
                                              float* __restrict__ Psel,
                                              float* __restrict__ state, int t) {
    int bg = blockIdx.x & 15, ut = blockIdx.x >> 4;
    int tid = threadIdx.x, w = tid >> 6, lane = tid & 63;
    int n = SS - t, p = t & 1, np = p ^ 1;

    __shared__ float lgl[4][SS];                 // patched logits copies
    __shared__ int   acl[4][SS];
    __shared__ int   recl[4][8];                 // idx,l,r,nl,lm1,r2,v0,v1
    __shared__ float L01[4][2];
    __shared__ float cl[4][16], cr[4][16], lm1s[4][16], r2s[4][16], hn[4][16];
    __shared__ __align__(16) float4 sp4[4][20][17];  // [b][colquad][ks16+pad]
    __shared__ float a_l[4][5][16];
    __shared__ float ppex[4][2][2][SELD];        // [b][pair][half][k]

    // ---- phase 1: refresh values for the 2 holes (prev step's Psel partials) ----
    if (t > 0 && tid < 256) {
        int b = bg * 4 + w;
        const int* rp = rec + ((size_t)p * NB + b) * 4;
        int pv0 = rp[1], pv1 = rp[2];
        if (pv0 | pv1) {
            float sA0 = bs1[lane], sA1 = bs1[lane + 64];
            float sB0 = sA0, sB1 = sA1;
            const float* Pb = Psel + ((size_t)(p * NB + b) * 16) * 256;
#pragma unroll
            for (int u2 = 0; u2 < 16; u2++) {
                const float* Pu = Pb + u2 * 256;
                sA0 += Pu[lane]; sA1 += Pu[lane + 64];
                sB0 += Pu[128 + lane]; sB1 += Pu[128 + lane + 64];
            }
            float yA = tanhf(sA0) * Ws2[lane] + tanhf(sA1) * Ws2[lane + 64];
            float yB = tanhf(sB0) * Ws2[lane] + tanhf(sB1) * Ws2[lane + 64];
#pragma unroll
            for (int off = 1; off < 64; off <<= 1) {
                yA += __shfl_xor(yA, off);
                yB += __shfl_xor(yB, off);
            }
            if (lane == 0) { L01[w][0] = yA + bs2[0]; L01[w][1] = yB + bs2[0]; }
        }
    }
    __syncthreads();

    // ---- phase 2: patch + argmax (numpy first-max) ----
    if (tid < 256) {
        int b = bg * 4 + w;
        const float* lgp = logits + ((size_t)p * NB + b) * SS;
        const int* acp = acts + ((size_t)p * NB + b) * SS;
        const int* rp = rec + ((size_t)p * NB + b) * 4;
        int pidx = rp[0], pv0 = rp[1], pv1 = rp[2], freerow = rp[3];
        int j0 = lane, j1 = lane + 64;
        float x0v = (j0 <= n - 2) ? lgp[j0] : -3.0e38f;
        float x1v = (j1 <= n - 2) ? lgp[j1] : -3.0e38f;
        acl[w][j0] = acp[j0];
        if (j1 < SS) acl[w][j1] = acp[j1];
        if (t > 0) {
            if (pv0) { if (j0 == pidx - 1) x0v = L01[w][0]; if (j1 == pidx - 1) x1v = L01[w][0]; }
            if (pv1) { if (j0 == pidx)     x0v = L01[w][1]; if (j1 == pidx)     x1v = L01[w][1]; }
        }
        if (j0 <= n - 2) lgl[w][j0] = x0v;
        if (j1 <= n - 2) lgl[w][j1] = x1v;
        float v = x0v; int i = j0;
        if (x1v > v) { v = x1v; i = j1; }
#pragma unroll
        for (int off = 1; off < 64; off <<= 1) {
            float ov = __shfl_xor(v, off);
            int oi = __shfl_xor(i, off);
            if (ov > v || (ov == v && oi < i)) { v = ov; i = oi; }
        }
        if (lane == 0) {
            int idx = i, l = acl[w][idx], r = acl[w][idx + 1];
            int v0 = (idx >= 1), v1 = (idx <= n - 3);
            recl[w][0] = idx; recl[w][1] = l; recl[w][2] = r; recl[w][3] = freerow;
            recl[w][4] = v0 ? acl[w][idx - 1] : 0;
            recl[w][5] = v1 ? acl[w][idx + 2] : 0;
            recl[w][6] = v0; recl[w][7] = v1;
        }
    }
    __syncthreads();

    // ---- stage small slices (c of l/r; h-slices of lm1/r2) ----
    if (tid < 256) {
        int which = tid >> 6, b2 = (tid >> 4) & 3, u = tid & 15;
        const float* sb = state + (size_t)(bg * 4 + b2) * RB * DD;
        if (which == 0)      cl[b2][u]   = sb[(size_t)recl[b2][1] * DD + ut * 16 + u];
        else if (which == 1) cr[b2][u]   = sb[(size_t)recl[b2][2] * DD + ut * 16 + u];
        else if (which == 2) lm1s[b2][u] = sb[(size_t)recl[b2][4] * DD + HH + ut * 16 + u];
        else                 r2s[b2][u]  = sb[(size_t)recl[b2][5] * DD + HH + ut * 16 + u];
    }

    // ---- phase 7 (ut==0): shift bookkeeping into parity t+1 (overlaps matvec) ----
    if (ut == 0 && tid < 256) {
        int b = bg * 4 + w;
        int idx = recl[w][0], l = recl[w][1], nl = recl[w][3];
        int* acn = acts + ((size_t)np * NB + b) * SS;
        float* lgn = logits + ((size_t)np * NB + b) * SS;
        for (int j = lane; j <= n - 2; j += 64)
            acn[j] = (j < idx) ? acl[w][j] : ((j == idx) ? nl : acl[w][j + 1]);
        for (int j = lane; j <= n - 3; j += 64)
            if (j != idx - 1 && j != idx)
                lgn[j] = (j < idx - 1) ? lgl[w][j] : lgl[w][j + 1];
        if (lane == 0) {
            int* rn = rec + ((size_t)np * NB + b) * 4;
            rn[0] = idx; rn[1] = recl[w][6]; rn[2] = recl[w][7]; rn[3] = l;
            nlUsed[b] = nl;
        }
    }

    // ---- phase 4: compose matvec (all 640 threads) ----
    {
        int b2 = tid / 320;                       // batch pair
        int r2m = tid % 320;
        int ks = r2m / 20;                        // 0..15, K-slice of 32 elems
        int cq = r2m % 20;                        // col quad
        int g = cq >> 2, q = cq & 3;
        int colb = g * 256 + ut * 16 + q * 4;
        int bA = b2 * 2, bB = bA + 1;
        int rowA = (ks < 8) ? recl[bA][1] : recl[bA][2];
        int rowB = (ks < 8) ? recl[bB][1] : recl[bB][2];
        const float4* xA = (const float4*)(state + ((size_t)(bg * 4 + bA) * RB + rowA) * DD + HH)
                           + (ks & 7) * 8;
        const float4* xB = (const float4*)(state + ((size_t)(bg * 4 + bB) * RB + rowB) * DD + HH)
                           + (ks & 7) * 8;
        const float* wb = Wc + (size_t)(ks * 32) * CK + colb;
        float4 accA = make_float4(0.f, 0.f, 0.f, 0.f);
        float4 accB = make_float4(0.f, 0.f, 0.f, 0.f);
#pragma unroll
        for (int i = 0; i < 8; i++) {
            float4 xvA = xA[i];
            float4 xvB = xB[i];
            const float* wr = wb + (size_t)(i * 4) * CK;
            float4 w0 = *(const float4*)(wr);
            float4 w1 = *(const float4*)(wr + CK);
            float4 w2v = *(const float4*)(wr + 2 * CK);
            float4 w3v = *(const float4*)(wr + 3 * CK);
            accA.x += xvA.x * w0.x + xvA.y * w1.x + xvA.z * w2v.x + xvA.w * w3v.x;
            accA.y += xvA.x * w0.y + xvA.y * w1.y + xvA.z * w2v.y + xvA.w * w3v.y;
            accA.z += xvA.x * w0.z + xvA.y * w1.z + xvA.z * w2v.z + xvA.w * w3v.z;
            accA.w += xvA.x * w0.w + xvA.y * w1.w + xvA.z * w2v.w + xvA.w * w3v.w;
            accB.x += xvB.x * w0.x + xvB.y * w1.x + xvB.z * w2v.x + xvB.w * w3v.x;
            accB.y += xvB.x * w0.y + xvB.y * w1.y + xvB.z * w2v.y + xvB.w * w3v.y;
            accB.z += xvB.x * w0.z + xvB.y * w1.z + xvB.z * w2v.z + xvB.w * w3v.z;
            accB.w += xvB.x * w0.w + xvB.y * w1.w + xvB.z * w2v.w + xvB.w * w3v.w;
        }
        sp4[bA][cq][ks] = accA;
        sp4[bB][cq][ks] = accB;
    }
    __syncthreads();

    // ---- reduce K-partials + bias ----
    if (tid < 320) {
        int b = tid / 80, colIdx = tid % 80;
        int g = colIdx >> 4, u = colIdx & 15;
        int cq = colIdx >> 2, e = colIdx & 3;
        float a = 0.f;
#pragma unroll
        for (int ks = 0; ks < 16; ks++) a += ((const float*)&sp4[b][cq][ks])[e];
        a_l[b][g][u] = a + bcomp[g * 256 + ut * 16 + u];
    }
    __syncthreads();

    // ---- phase 5: gates + write composed c,h into fresh row ----
    if (tid < 64) {
        int b = tid >> 4, u = tid & 15;
        float ai = a_l[b][0][u], afl = a_l[b][1][u], afr = a_l[b][2][u];
        float ao = a_l[b][3][u], agc = a_l[b][4][u];
        float si  = 1.f / (1.f + expf(-ai));
        float sfl = 1.f / (1.f + expf(-afl));
        float sfr = 1.f / (1.f + expf(-afr));
        float so  = 1.f / (1.f + expf(-ao));
        float cv = sfl * cl[b][u] + sfr * cr[b][u] + si * tanhf(agc);
        float hv = so * tanhf(cv);
        float* sb = state + (size_t)(bg * 4 + b) * RB * DD;
        int nl = recl[b][3];
        sb[(size_t)nl * DD + ut * 16 + u] = cv;
        sb[(size_t)nl * DD + HH + ut * 16 + u] = hv;
        hn[b][u] = hv;
    }
    __syncthreads();

    // ---- phase 6: sel partials for next step's 2 refreshed pairs (own 32 x-dims) ----
    if (tid < 256) {
        int kk = tid & 127, half = tid >> 7;
        int e4base = half * 64 + ut * 4;
        const float4* W4 = (const float4*)Ws4;
        float P0[4] = {0.f, 0.f, 0.f, 0.f}, P1[4] = {0.f, 0.f, 0.f, 0.f};
#pragma unroll
        for (int j = 0; j < 4; j++) {
            float4 wv = W4[(size_t)(e4base + j) * SELD + kk];
#pragma unroll
            for (int b4 = 0; b4 < 4; b4++) {
                const float* xa0 = half ? hn[b4] : lm1s[b4];   // pair0: [h_lm1 | h_new]
                const float* xa1 = half ? r2s[b4] : hn[b4];    // pair1: [h_new | h_r2]
                P0[b4] += wv.x * xa0[4 * j] + wv.y * xa0[4 * j + 1]
                        + wv.z * xa0[4 * j + 2] + wv.w * xa0[4 * j + 3];
                P1[b4] += wv.x * xa1[4 * j] + wv.y * xa1[4 * j + 1]
                        + wv.z * xa1[4 * j + 2] + wv.w * xa1[4 * j + 3];
            }
        }
#pragma unroll
        for (int b4 = 0; b4 < 4; b4++) {
            ppex[b4][0][half][kk] = P0[b4];
            ppex[b4][1][half][kk] = P1[b4];
        }
    }
    __syncthreads();
    if (tid < 256) {
        int kk = tid & 127, pr = tid >> 7;
#pragma unroll
        for (int b4 = 0; b4 < 4; b4++) {
            int b = bg * 4 + b4;
            Psel[((size_t)(np * NB + b) * 16 + ut) * 256 + pr * 128 + kk] =
                ppex[b4][pr][0][kk] + ppex[b4][pr][1][kk];
        }
    }
}

// ---------------- MLP head, column-parallel ------------------------------------------------------
__global__ __launch_bounds__(256) void k_mlp1(const float* __restrict__ state,
                                              const int* __restrict__ nlUsed,
                                              const float* __restrict__ Wm1,
                                              const float* __restrict__ bm1,
                                              float* __restrict__ x1g) {
    int b = blockIdx.x >> 2, q = blockIdx.x & 3, tid = threadIdx.x;
    int col = q * 256 + tid;
    __shared__ float x0[HH];
    int root = nlUsed[b];
    x0[tid] = state[((size_t)b * RB + root) * DD + HH + tid];
    __syncthreads();
    float acc = bm1[col];
    for (int e = 0; e < HH; e++) acc += x0[e] * Wm1[(size_t)e * MLPD + col];
    x1g[(size_t)b * MLPD + col] = fmaxf(acc, 0.f);
}

__global__ __launch_bounds__(128) void k_mlp2(const float* __restrict__ x1g,
                                              const float* __restrict__ Wm2,
                                              const float* __restrict__ bm2,
                                              float* __restrict__ x2g) {
    int b = blockIdx.x >> 3, q = blockIdx.x & 7, tid = threadIdx.x;
    int col = q * 128 + tid;
    __shared__ __align__(16) float x1[MLPD];
    for (int i = tid; i < 256; i += 128)
        ((float4*)x1)[i] = ((const float4*)(x1g + (size_t)b * MLPD))[i];
    __syncthreads();
    float acc = bm2[col];
    for (int e = 0; e < MLPD; e++) acc += x1[e] * Wm2[(size_t)e * MLPD + col];
    x2g[(size_t)b * MLPD + col] = fmaxf(acc, 0.f);
}

__global__ __launch_bounds__(256) void k_mlp3(const float* __restrict__ x2g,
                                              const float* __restrict__ Wout,
                                              const float* __restrict__ bout,
                                              float* __restrict__ out) {
    int b = blockIdx.x, tid = threadIdx.x;
    __shared__ __align__(16) float x2[MLPD];
    __shared__ float red3[3][256];
    ((float4*)x2)[tid] = ((const float4*)(x2g + (size_t)b * MLPD))[tid];
    __syncthreads();
    float p0 = 0.f, p1 = 0.f, p2 = 0.f;
    for (int e = tid; e < MLPD; e += 256) {
        float x = x2[e];
        p0 += x * Wout[e * NCLS + 0];
        p1 += x * Wout[e * NCLS + 1];
        p2 += x * Wout[e * NCLS + 2];
    }
    red3[0][tid] = p0; red3[1][tid] = p1; red3[2][tid] = p2;
    __syncthreads();
    for (int sdd = 128; sdd >= 1; sdd >>= 1) {
        if (tid < sdd) {
            red3[0][tid] += red3[0][tid + sdd];
            red3[1][tid] += red3[1][tid + sdd];
            red3[2][tid] += red3[2][tid + sdd];
        }
        __syncthreads();
    }
    if (tid < NCLS) out[b * NCLS + tid] = red3[tid][0] + bout[tid];
}

extern "C" void kernel_launch(void* const* d_in, const int* in_sizes, int n_in,
                              void* d_out, int out_size, void* d_ws, size_t ws_size,
                              hipStream_t stream) {
    const int*   sent  = (const int*)d_in[0];
    // d_in[1] = transitions: unused by the reference
    const float* emb   = (const float*)d_in[2];
    const float* Wenc  = (const float*)d_in[3];
    const float* benc  = (const float*)d_in[4];
    const float* Wcomp = (const float*)d_in[5];
    const float* bcomp = (const float*)d_in[6];
    const float* Wsel1 = (const float*)d_in[7];
    const float* bs1   = (const float*)d_in[8];
    const float* Ws2   = (const float*)d_in[9];
    const float* bs2   = (const float*)d_in[10];
    const float* Wm1   = (const float*)d_in[11];
    const float* bm1   = (const float*)d_in[12];
    const float* Wm2   = (const float*)d_in[13];
    const float* bm2   = (const float*)d_in[14];
    const float* Wout  = (const float*)d_in[15];
    const float* bout  = (const float*)d_in[16];
    float* out = (float*)d_out;

    float* ws     = (float*)d_ws;
    float* state  = ws;                              // 3,178,496 f32
    float* Ws14   = ws + 3178496;                    // 65,536
    float* logits = ws + 3244032;                    // 2*64*96 = 12,288 (ping-pong)
    int*   acts   = (int*)(ws + 3256320);            // 12,288 ints (ping-pong)
    int*   rec    = (int*)(ws + 3268608);            // 512 ints (ping-pong)
    int*   nlUsed = (int*)(ws + 3269120);            // 64 ints
    float* Psel   = ws + 3269184;                    // 2*64*16*256 = 524,288 (ping-pong)
    float* x1g    = ws + 3269184;                    // alias: Psel dead after scan
    float* x2g    = ws + 3334720;                    // alias

    k_trans_sel<<<dim3(128), dim3(128), 0, stream>>>(Wsel1, Ws14);
    k_init<<<dim3(NB), dim3(SS), 0, stream>>>(acts, rec);
    k_encode<<<dim3(NB * 6), dim3(256), 0, stream>>>(sent, emb, Wenc, benc, state);
    k_logits0<<<dim3(NB * 5), dim3(128), 0, stream>>>(state, Ws14, bs1, Ws2, bs2, logits);

    for (int t = 0; t < SS - 1; t++)   // t = 0..94
        k_step<<<dim3(256), dim3(640), 0, stream>>>(Wcomp, bcomp, Ws14, bs1, Ws2, bs2,
                                                    logits, acts, rec, nlUsed, Psel, state, t);

    k_mlp1<<<dim3(NB * 4), dim3(256), 0, stream>>>(state, nlUsed, Wm1, bm1, x1g);
    k_mlp2<<<dim3(NB * 8), dim3(128), 0, stream>>>(x1g, Wm2, bm2, x2g);
    k_mlp3<<<dim3(NB), dim3(256), 0, stream>>>(x2g, Wout, bout, out);
}

// Round 8
// 1249.818 us; speedup vs baseline: 1.5806x; 1.1045x over previous
//
#include <hip/hip_runtime.h>
#include <math.h>

#define NB   64
#define SS   96
#define EE   300
#define DD   512
#define HH   256
#define SELD 128
#define CK   1280   // 5*H
#define MLPD 1024
#define NCLS 3
#define RB   97     // state rows per batch: 96 initial + 1 spare (freed-row recycling)

// ---------------- transpose W_sel1 [e][k] -> [e4][k] float4 (4 consecutive e rows at col k) ------
__global__ void k_trans_sel(const float* __restrict__ Ws, float* __restrict__ Ws4) {
    int e4 = blockIdx.x;            // 0..127
    int k = threadIdx.x;            // 0..127
    float4 v;
    v.x = Ws[(4 * e4 + 0) * SELD + k];
    v.y = Ws[(4 * e4 + 1) * SELD + k];
    v.z = Ws[(4 * e4 + 2) * SELD + k];
    v.w = Ws[(4 * e4 + 3) * SELD + k];
    ((float4*)Ws4)[e4 * SELD + k] = v;
}

// ---------------- init parity-0 bookkeeping ------------------------------------------------------
__global__ void k_init(int* __restrict__ acts, int* __restrict__ rec) {
    int b = blockIdx.x, tid = threadIdx.x;
    acts[b * SS + tid] = tid;                     // parity-0
    if (tid == 0) {
        int* r = rec + b * 4;                     // parity-0
        r[0] = 0; r[1] = 0; r[2] = 0; r[3] = SS;  // pidx, pv0, pv1, freerow
    }
}

// ---------------- encode v6: 768 blocks (b x 3 s-tiles x 4 col-quarters), 2 s x 8 cols/thread ---
__global__ __launch_bounds__(256) void k_encode(const int* __restrict__ sent,
                                                const float* __restrict__ emb,
                                                const float* __restrict__ Wenc,
                                                const float* __restrict__ benc,
                                                float* __restrict__ state) {
    int bi = blockIdx.x;
    int b = bi / 12, rem = bi % 12, tile = rem >> 2, ch = rem & 3;
    int s0 = tile * 32, col0 = ch * 128;
    __shared__ int tok[32];
    __shared__ __align__(16) float elds[32 * 300];
    int tid = threadIdx.x;
    if (tid < 32) tok[tid] = sent[b * SS + s0 + tid];
    __syncthreads();
    {
        const float4* e4p = (const float4*)emb;
        float4* l4s = (float4*)elds;
        for (int i4 = tid; i4 < 32 * 75; i4 += 256) {
            int s = i4 / 75, r = i4 - s * 75;
            l4s[i4] = e4p[(size_t)tok[s] * 75 + r];
        }
    }
    __syncthreads();
    int cg = tid & 15, sg = tid >> 4;            // 16 col-octets, 16 s-groups x 2 sents
    int colb = col0 + cg * 8, sb = sg * 2;
    float4 aA0, aA1, aB0, aB1;
    {
        float4 bA = *(const float4*)&benc[colb];
        float4 bB = *(const float4*)&benc[colb + 4];
        aA0 = bA; aA1 = bA; aB0 = bB; aB1 = bB;
    }
    const float4* l4 = (const float4*)elds;
    for (int e4 = 0; e4 < 75; e4++) {
        float4 wA[4], wB[4];
#pragma unroll
        for (int j = 0; j < 4; j++) {
            const float* wr = Wenc + (size_t)(4 * e4 + j) * DD + colb;
            wA[j] = *(const float4*)wr;
            wB[j] = *(const float4*)(wr + 4);
        }
        float4 x0 = l4[(sb + 0) * 75 + e4];
        float4 x1 = l4[(sb + 1) * 75 + e4];
        aA0.x += x0.x * wA[0].x + x0.y * wA[1].x + x0.z * wA[2].x + x0.w * wA[3].x;
        aA0.y += x0.x * wA[0].y + x0.y * wA[1].y + x0.z * wA[2].y + x0.w * wA[3].y;
        aA0.z += x0.x * wA[0].z + x0.y * wA[1].z + x0.z * wA[2].z + x0.w * wA[3].z;
        aA0.w += x0.x * wA[0].w + x0.y * wA[1].w + x0.z * wA[2].w + x0.w * wA[3].w;
        aB0.x += x0.x * wB[0].x + x0.y * wB[1].x + x0.z * wB[2].x + x0.w * wB[3].x;
        aB0.y += x0.x * wB[0].y + x0.y * wB[1].y + x0.z * wB[2].y + x0.w * wB[3].y;
        aB0.z += x0.x * wB[0].z + x0.y * wB[1].z + x0.z * wB[2].z + x0.w * wB[3].z;
        aB0.w += x0.x * wB[0].w + x0.y * wB[1].w + x0.z * wB[2].w + x0.w * wB[3].w;
        aA1.x += x1.x * wA[0].x + x1.y * wA[1].x + x1.z * wA[2].x + x1.w * wA[3].x;
        aA1.y += x1.x * wA[0].y + x1.y * wA[1].y + x1.z * wA[2].y + x1.w * wA[3].y;
        aA1.z += x1.x * wA[0].z + x1.y * wA[1].z + x1.z * wA[2].z + x1.w * wA[3].z;
        aA1.w += x1.x * wA[0].w + x1.y * wA[1].w + x1.z * wA[2].w + x1.w * wA[3].w;
        aB1.x += x1.x * wB[0].x + x1.y * wB[1].x + x1.z * wB[2].x + x1.w * wB[3].x;
        aB1.y += x1.x * wB[0].y + x1.y * wB[1].y + x1.z * wB[2].y + x1.w * wB[3].y;
        aB1.z += x1.x * wB[0].z + x1.y * wB[1].z + x1.z * wB[2].z + x1.w * wB[3].z;
        aB1.w += x1.x * wB[0].w + x1.y * wB[1].w + x1.z * wB[2].w + x1.w * wB[3].w;
    }
    {
        float* dst = state + ((size_t)b * RB + s0 + sb) * DD + colb;
        *(float4*)dst = aA0;
        *(float4*)(dst + 4) = aB0;
        dst += DD;
        *(float4*)dst = aA1;
        *(float4*)(dst + 4) = aB1;
    }
}

// ---------------- initial logits for all 95 pairs per batch (parity-0), 256 threads --------------
__global__ __launch_bounds__(256) void k_logits0(const float* __restrict__ state,
                                                 const float* __restrict__ Ws4,
                                                 const float* __restrict__ bs1,
                                                 const float* __restrict__ Ws2,
                                                 const float* __restrict__ bs2,
                                                 float* __restrict__ logits) {
    int b = blockIdx.x / 5, tile = blockIdx.x % 5, p0 = tile * 19;
    __shared__ __align__(16) float hl[20 * 256];
    __shared__ float part[2][2][10];
    int tid = threadIdx.x;
    for (int i = tid; i < 20 * 256; i += 256) {
        int r = i >> 8, c = i & 255;
        hl[i] = state[((size_t)b * RB + p0 + r) * DD + HH + c];
    }
    __syncthreads();
    int k = tid & 127, ph = tid >> 7;            // ph=0: pairs 0..9, ph=1: pairs 10..18
    int npair = ph ? 9 : 10, pbase = ph * 10;
    float acc[10];
#pragma unroll
    for (int pp = 0; pp < 10; pp++) acc[pp] = 0.f;
    const float4* W4 = (const float4*)Ws4;
    const float4* h4 = (const float4*)hl;
    for (int e4 = 0; e4 < 128; e4++) {
        float4 w = W4[e4 * SELD + k];
#pragma unroll
        for (int pp = 0; pp < 10; pp++) {
            float4 x = h4[(pbase + pp) * 64 + e4];   // row pbase+pp<19 guaranteed used only
            acc[pp] += x.x * w.x + x.y * w.y + x.z * w.z + x.w * w.w;
        }
    }
    float b1 = bs1[k], w2 = Ws2[k];
    int wid = (tid >> 6) & 1, lane = tid & 63;
#pragma unroll
    for (int pp = 0; pp < 10; pp++) {
        float y = (pp < npair) ? tanhf(acc[pp] + b1) * w2 : 0.f;
        for (int off = 32; off >= 1; off >>= 1) y += __shfl_down(y, off);
        if (lane == 0 && pp < npair) part[ph][wid][pp] = y;
    }
    __syncthreads();
    if (tid < 19) {
        int ph2 = tid / 10, pp = tid - ph2 * 10;
        logits[b * SS + p0 + tid] = part[ph2][0][pp] + part[ph2][1][pp] + bs2[0];
    }
}

// ---------------- fused step kernel v5: 256 blocks = 16 bg x 16 ut; 640 threads ------------------
// Matvec thread = (ks:32, cq:20); ALL 4 batches amortized in regs per W float4 (W dup 1x).
__global__ __launch_bounds__(640) void k_step(const float* __restrict__ Wc,
                                              const float* __restrict__ bcomp,
                                              const float* __restrict__ Ws4,
                                              const float* __restrict__ bs1,
                                              const float* __restrict__ Ws2,
                                              const float* __restrict__ bs2,
                                              float* __restrict__ logits,
                                              int* __restrict__ acts,
                                              int* __restrict__ rec,
                                              int* __restrict__ nlUsed,
                                              float* __restrict__ Psel,
                                              float* __restrict__ state, int t) {
    int bg = blockIdx.x & 15, ut = blockIdx.x >> 4;
    int tid = threadIdx.x, w = tid >> 6, lane = tid & 63;
    int n = SS - t, p = t & 1, np = p ^ 1;

    __shared__ float lgl[4][SS];                 // patched logits copies
    __shared__ int   acl[4][SS];
    __shared__ int   recl[4][8];                 // idx,l,r,nl,lm1,r2,v0,v1
    __shared__ float L01[4][2];
    __shared__ float cl[4][16], cr[4][16], lm1s[4][16], r2s[4][16], hn[4][16];
    __shared__ __align__(16) float4 sp4[4][20][33];  // [b][colquad][ks32+pad]
    __shared__ float a_l[4][5][16];
    __shared__ float ppex[4][2][2][SELD];        // [b][pair][half][k]

    // ---- prefetch phase-6 Ws4 fragments (addresses block-static) ----
    float4 pw0, pw1, pw2, pw3;
    {
        int kk = tid & 127, half = (tid >> 7) & 1;
        int e4base = half * 64 + ut * 4;
        const float4* W4 = (const float4*)Ws4;
        pw0 = W4[(size_t)(e4base + 0) * SELD + kk];
        pw1 = W4[(size_t)(e4base + 1) * SELD + kk];
        pw2 = W4[(size_t)(e4base + 2) * SELD + kk];
        pw3 = W4[(size_t)(e4base + 3) * SELD + kk];
    }

    // ---- phase 1: refresh values for the 2 holes (prev step's Psel partials) ----
    if (t > 0 && tid < 256) {
        int b = bg * 4 + w;
        const int* rp = rec + ((size_t)p * NB + b) * 4;
        int pv0 = rp[1], pv1 = rp[2];
        if (pv0 | pv1) {
            float sA0 = bs1[lane], sA1 = bs1[lane + 64];
            float sB0 = sA0, sB1 = sA1;
            const float* Pb = Psel + ((size_t)(p * NB + b) * 16) * 256;
#pragma unroll
            for (int u2 = 0; u2 < 16; u2++) {
                const float* Pu = Pb + u2 * 256;
                sA0 += Pu[lane]; sA1 += Pu[lane + 64];
                sB0 += Pu[128 + lane]; sB1 += Pu[128 + lane + 64];
            }
            float yA = tanhf(sA0) * Ws2[lane] + tanhf(sA1) * Ws2[lane + 64];
            float yB = tanhf(sB0) * Ws2[lane] + tanhf(sB1) * Ws2[lane + 64];
#pragma unroll
            for (int off = 1; off < 64; off <<= 1) {
                yA += __shfl_xor(yA, off);
                yB += __shfl_xor(yB, off);
            }
            if (lane == 0) { L01[w][0] = yA + bs2[0]; L01[w][1] = yB + bs2[0]; }
        }
    }
    __syncthreads();

    // ---- phase 2: patch + argmax (numpy first-max) ----
    if (tid < 256) {
        int b = bg * 4 + w;
        const float* lgp = logits + ((size_t)p * NB + b) * SS;
        const int* acp = acts + ((size_t)p * NB + b) * SS;
        const int* rp = rec + ((size_t)p * NB + b) * 4;
        int pidx = rp[0], pv0 = rp[1], pv1 = rp[2], freerow = rp[3];
        int j0 = lane, j1 = lane + 64;
        float x0v = (j0 <= n - 2) ? lgp[j0] : -3.0e38f;
        float x1v = (j1 <= n - 2) ? lgp[j1] : -3.0e38f;
        acl[w][j0] = acp[j0];
        if (j1 < SS) acl[w][j1] = acp[j1];
        if (t > 0) {
            if (pv0) { if (j0 == pidx - 1) x0v = L01[w][0]; if (j1 == pidx - 1) x1v = L01[w][0]; }
            if (pv1) { if (j0 == pidx)     x0v = L01[w][1]; if (j1 == pidx)     x1v = L01[w][1]; }
        }
        if (j0 <= n - 2) lgl[w][j0] = x0v;
        if (j1 <= n - 2) lgl[w][j1] = x1v;
        float v = x0v; int i = j0;
        if (x1v > v) { v = x1v; i = j1; }
#pragma unroll
        for (int off = 1; off < 64; off <<= 1) {
            float ov = __shfl_xor(v, off);
            int oi = __shfl_xor(i, off);
            if (ov > v || (ov == v && oi < i)) { v = ov; i = oi; }
        }
        if (lane == 0) {
            int idx = i, l = acl[w][idx], r = acl[w][idx + 1];
            int v0 = (idx >= 1), v1 = (idx <= n - 3);
            recl[w][0] = idx; recl[w][1] = l; recl[w][2] = r; recl[w][3] = freerow;
            recl[w][4] = v0 ? acl[w][idx - 1] : 0;
            recl[w][5] = v1 ? acl[w][idx + 2] : 0;
            recl[w][6] = v0; recl[w][7] = v1;
        }
    }
    __syncthreads();

    // ---- stage small slices (c of l/r; h-slices of lm1/r2) ----
    if (tid < 256) {
        int which = tid >> 6, b2 = (tid >> 4) & 3, u = tid & 15;
        const float* sb = state + (size_t)(bg * 4 + b2) * RB * DD;
        if (which == 0)      cl[b2][u]   = sb[(size_t)recl[b2][1] * DD + ut * 16 + u];
        else if (which == 1) cr[b2][u]   = sb[(size_t)recl[b2][2] * DD + ut * 16 + u];
        else if (which == 2) lm1s[b2][u] = sb[(size_t)recl[b2][4] * DD + HH + ut * 16 + u];
        else                 r2s[b2][u]  = sb[(size_t)recl[b2][5] * DD + HH + ut * 16 + u];
    }

    // ---- phase 7 (ut==0): shift bookkeeping into parity t+1 (overlaps matvec) ----
    if (ut == 0 && tid < 256) {
        int b = bg * 4 + w;
        int idx = recl[w][0], l = recl[w][1], nl = recl[w][3];
        int* acn = acts + ((size_t)np * NB + b) * SS;
        float* lgn = logits + ((size_t)np * NB + b) * SS;
        for (int j = lane; j <= n - 2; j += 64)
            acn[j] = (j < idx) ? acl[w][j] : ((j == idx) ? nl : acl[w][j + 1]);
        for (int j = lane; j <= n - 3; j += 64)
            if (j != idx - 1 && j != idx)
                lgn[j] = (j < idx - 1) ? lgl[w][j] : lgl[w][j + 1];
        if (lane == 0) {
            int* rn = rec + ((size_t)np * NB + b) * 4;
            rn[0] = idx; rn[1] = recl[w][6]; rn[2] = recl[w][7]; rn[3] = l;
            nlUsed[b] = nl;
        }
    }

    // ---- phase 4: compose matvec; thread = (ks:32, cq:20); 4 batches in regs ----
    {
        int ks = tid / 20, cq = tid - (tid / 20) * 20;
        int g = cq >> 2, q = cq & 3;
        int colb = g * 256 + ut * 16 + q * 4;
        int hoff = (ks & 15) * 4;                 // f4 offset within the h half
        bool leftHalf = (ks < 16);
        const float4* x0p = (const float4*)(state + ((size_t)(bg * 4 + 0) * RB +
                              (leftHalf ? recl[0][1] : recl[0][2])) * DD + HH) + hoff;
        const float4* x1p = (const float4*)(state + ((size_t)(bg * 4 + 1) * RB +
                              (leftHalf ? recl[1][1] : recl[1][2])) * DD + HH) + hoff;
        const float4* x2p = (const float4*)(state + ((size_t)(bg * 4 + 2) * RB +
                              (leftHalf ? recl[2][1] : recl[2][2])) * DD + HH) + hoff;
        const float4* x3p = (const float4*)(state + ((size_t)(bg * 4 + 3) * RB +
                              (leftHalf ? recl[3][1] : recl[3][2])) * DD + HH) + hoff;
        const float* wb = Wc + (size_t)(ks * 16) * CK + colb;
        float4 a0 = make_float4(0.f, 0.f, 0.f, 0.f);
        float4 a1 = a0, a2 = a0, a3 = a0;
#pragma unroll
        for (int i4 = 0; i4 < 4; i4++) {
            float4 xv0 = x0p[i4], xv1 = x1p[i4], xv2 = x2p[i4], xv3 = x3p[i4];
            const float* wr = wb + (size_t)(i4 * 4) * CK;
            float4 w0 = *(const float4*)(wr);
            float4 w1 = *(const float4*)(wr + CK);
            float4 w2v = *(const float4*)(wr + 2 * CK);
            float4 w3v = *(const float4*)(wr + 3 * CK);
            a0.x += xv0.x * w0.x + xv0.y * w1.x + xv0.z * w2v.x + xv0.w * w3v.x;
            a0.y += xv0.x * w0.y + xv0.y * w1.y + xv0.z * w2v.y + xv0.w * w3v.y;
            a0.z += xv0.x * w0.z + xv0.y * w1.z + xv0.z * w2v.z + xv0.w * w3v.z;
            a0.w += xv0.x * w0.w + xv0.y * w1.w + xv0.z * w2v.w + xv0.w * w3v.w;
            a1.x += xv1.x * w0.x + xv1.y * w1.x + xv1.z * w2v.x + xv1.w * w3v.x;
            a1.y += xv1.x * w0.y + xv1.y * w1.y + xv1.z * w2v.y + xv1.w * w3v.y;
            a1.z += xv1.x * w0.z + xv1.y * w1.z + xv1.z * w2v.z + xv1.w * w3v.z;
            a1.w += xv1.x * w0.w + xv1.y * w1.w + xv1.z * w2v.w + xv1.w * w3v.w;
            a2.x += xv2.x * w0.x + xv2.y * w1.x + xv2.z * w2v.x + xv2.w * w3v.x;
            a2.y += xv2.x * w0.y + xv2.y * w1.y + xv2.z * w2v.y + xv2.w * w3v.y;
            a2.z += xv2.x * w0.z + xv2.y * w1.z + xv2.z * w2v.z + xv2.w * w3v.z;
            a2.w += xv2.x * w0.w + xv2.y * w1.w + xv2.z * w2v.w + xv2.w * w3v.w;
            a3.x += xv3.x * w0.x + xv3.y * w1.x + xv3.z * w2v.x + xv3.w * w3v.x;
            a3.y += xv3.x * w0.y + xv3.y * w1.y + xv3.z * w2v.y + xv3.w * w3v.y;
            a3.z += xv3.x * w0.z + xv3.y * w1.z + xv3.z * w2v.z + xv3.w * w3v.z;
            a3.w += xv3.x * w0.w + xv3.y * w1.w + xv3.z * w2v.w + xv3.w * w3v.w;
        }
        sp4[0][cq][ks] = a0;
        sp4[1][cq][ks] = a1;
        sp4[2][cq][ks] = a2;
        sp4[3][cq][ks] = a3;
    }
    __syncthreads();

    // ---- reduce K-partials + bias ----
    if (tid < 320) {
        int b = tid / 80, colIdx = tid % 80;
        int g = colIdx >> 4, u = colIdx & 15;
        int cq = colIdx >> 2, e = colIdx & 3;
        float a = 0.f;
#pragma unroll
        for (int ks = 0; ks < 32; ks++) a += ((const float*)&sp4[b][cq][ks])[e];
        a_l[b][g][u] = a + bcomp[g * 256 + ut * 16 + u];
    }
    __syncthreads();

    // ---- phase 5: gates + write composed c,h into fresh row ----
    if (tid < 64) {
        int b = tid >> 4, u = tid & 15;
        float ai = a_l[b][0][u], afl = a_l[b][1][u], afr = a_l[b][2][u];
        float ao = a_l[b][3][u], agc = a_l[b][4][u];
        float si  = 1.f / (1.f + expf(-ai));
        float sfl = 1.f / (1.f + expf(-afl));
        float sfr = 1.f / (1.f + expf(-afr));
        float so  = 1.f / (1.f + expf(-ao));
        float cv = sfl * cl[b][u] + sfr * cr[b][u] + si * tanhf(agc);
        float hv = so * tanhf(cv);
        float* sb = state + (size_t)(bg * 4 + b) * RB * DD;
        int nl = recl[b][3];
        sb[(size_t)nl * DD + ut * 16 + u] = cv;
        sb[(size_t)nl * DD + HH + ut * 16 + u] = hv;
        hn[b][u] = hv;
    }
    __syncthreads();

    // ---- phase 6: sel partials for next step's 2 refreshed pairs (own 32 x-dims) ----
    if (tid < 256) {
        int kk = tid & 127, half = tid >> 7;
        float P0[4] = {0.f, 0.f, 0.f, 0.f}, P1[4] = {0.f, 0.f, 0.f, 0.f};
#pragma unroll
        for (int b4 = 0; b4 < 4; b4++) {
            const float* xa0 = half ? hn[b4] : lm1s[b4];   // pair0: [h_lm1 | h_new]
            const float* xa1 = half ? r2s[b4] : hn[b4];    // pair1: [h_new | h_r2]
            P0[b4] += pw0.x * xa0[0] + pw0.y * xa0[1] + pw0.z * xa0[2] + pw0.w * xa0[3];
            P0[b4] += pw1.x * xa0[4] + pw1.y * xa0[5] + pw1.z * xa0[6] + pw1.w * xa0[7];
            P0[b4] += pw2.x * xa0[8] + pw2.y * xa0[9] + pw2.z * xa0[10] + pw2.w * xa0[11];
            P0[b4] += pw3.x * xa0[12] + pw3.y * xa0[13] + pw3.z * xa0[14] + pw3.w * xa0[15];
            P1[b4] += pw0.x * xa1[0] + pw0.y * xa1[1] + pw0.z * xa1[2] + pw0.w * xa1[3];
            P1[b4] += pw1.x * xa1[4] + pw1.y * xa1[5] + pw1.z * xa1[6] + pw1.w * xa1[7];
            P1[b4] += pw2.x * xa1[8] + pw2.y * xa1[9] + pw2.z * xa1[10] + pw2.w * xa1[11];
            P1[b4] += pw3.x * xa1[12] + pw3.y * xa1[13] + pw3.z * xa1[14] + pw3.w * xa1[15];
        }
#pragma unroll
        for (int b4 = 0; b4 < 4; b4++) {
            ppex[b4][0][half][kk] = P0[b4];
            ppex[b4][1][half][kk] = P1[b4];
        }
    }
    __syncthreads();
    if (tid < 256) {
        int kk = tid & 127, pr = tid >> 7;
#pragma unroll
        for (int b4 = 0; b4 < 4; b4++) {
            int b = bg * 4 + b4;
            Psel[((size_t)(np * NB + b) * 16 + ut) * 256 + pr * 128 + kk] =
                ppex[b4][pr][0][kk] + ppex[b4][pr][1][kk];
        }
    }
}

// ---------------- MLP head, column-parallel ------------------------------------------------------
__global__ __launch_bounds__(256) void k_mlp1(const float* __restrict__ state,
                                              const int* __restrict__ nlUsed,
                                              const float* __restrict__ Wm1,
                                              const float* __restrict__ bm1,
                                              float* __restrict__ x1g) {
    int b = blockIdx.x >> 2, q = blockIdx.x & 3, tid = threadIdx.x;
    int col = q * 256 + tid;
    __shared__ float x0[HH];
    int root = nlUsed[b];
    x0[tid] = state[((size_t)b * RB + root) * DD + HH + tid];
    __syncthreads();
    float acc = bm1[col];
    for (int e = 0; e < HH; e++) acc += x0[e] * Wm1[(size_t)e * MLPD + col];
    x1g[(size_t)b * MLPD + col] = fmaxf(acc, 0.f);
}

__global__ __launch_bounds__(128) void k_mlp2(const float* __restrict__ x1g,
                                              const float* __restrict__ Wm2,
                                              const float* __restrict__ bm2,
                                              float* __restrict__ x2g) {
    int b = blockIdx.x >> 3, q = blockIdx.x & 7, tid = threadIdx.x;
    int col = q * 128 + tid;
    __shared__ __align__(16) float x1[MLPD];
    for (int i = tid; i < 256; i += 128)
        ((float4*)x1)[i] = ((const float4*)(x1g + (size_t)b * MLPD))[i];
    __syncthreads();
    float acc = bm2[col];
    for (int e = 0; e < MLPD; e++) acc += x1[e] * Wm2[(size_t)e * MLPD + col];
    x2g[(size_t)b * MLPD + col] = fmaxf(acc, 0.f);
}

__global__ __launch_bounds__(256) void k_mlp3(const float* __restrict__ x2g,
                                              const float* __restrict__ Wout,
                                              const float* __restrict__ bout,
                                              float* __restrict__ out) {
    int b = blockIdx.x, tid = threadIdx.x;
    __shared__ __align__(16) float x2[MLPD];
    __shared__ float red3[3][256];
    ((float4*)x2)[tid] = ((const float4*)(x2g + (size_t)b * MLPD))[tid];
    __syncthreads();
    float p0 = 0.f, p1 = 0.f, p2 = 0.f;
    for (int e = tid; e < MLPD; e += 256) {
        float x = x2[e];
        p0 += x * Wout[e * NCLS + 0];
        p1 += x * Wout[e * NCLS + 1];
        p2 += x * Wout[e * NCLS + 2];
    }
    red3[0][tid] = p0; red3[1][tid] = p1; red3[2][tid] = p2;
    __syncthreads();
    for (int sdd = 128; sdd >= 1; sdd >>= 1) {
        if (tid < sdd) {
            red3[0][tid] += red3[0][tid + sdd];
            red3[1][tid] += red3[1][tid + sdd];
            red3[2][tid] += red3[2][tid + sdd];
        }
        __syncthreads();
    }
    if (tid < NCLS) out[b * NCLS + tid] = red3[tid][0] + bout[tid];
}

extern "C" void kernel_launch(void* const* d_in, const int* in_sizes, int n_in,
                              void* d_out, int out_size, void* d_ws, size_t ws_size,
                              hipStream_t stream) {
    const int*   sent  = (const int*)d_in[0];
    // d_in[1] = transitions: unused by the reference
    const float* emb   = (const float*)d_in[2];
    const float* Wenc  = (const float*)d_in[3];
    const float* benc  = (const float*)d_in[4];
    const float* Wcomp = (const float*)d_in[5];
    const float* bcomp = (const float*)d_in[6];
    const float* Wsel1 = (const float*)d_in[7];
    const float* bs1   = (const float*)d_in[8];
    const float* Ws2   = (const float*)d_in[9];
    const float* bs2   = (const float*)d_in[10];
    const float* Wm1   = (const float*)d_in[11];
    const float* bm1   = (const float*)d_in[12];
    const float* Wm2   = (const float*)d_in[13];
    const float* bm2   = (const float*)d_in[14];
    const float* Wout  = (const float*)d_in[15];
    const float* bout  = (const float*)d_in[16];
    float* out = (float*)d_out;

    float* ws     = (float*)d_ws;
    float* state  = ws;                              // 3,178,496 f32
    float* Ws14   = ws + 3178496;                    // 65,536
    float* logits = ws + 3244032;                    // 2*64*96 = 12,288 (ping-pong)
    int*   acts   = (int*)(ws + 3256320);            // 12,288 ints (ping-pong)
    int*   rec    = (int*)(ws + 3268608);            // 512 ints (ping-pong)
    int*   nlUsed = (int*)(ws + 3269120);            // 64 ints
    float* Psel   = ws + 3269184;                    // 2*64*16*256 = 524,288 (ping-pong)
    float* x1g    = ws + 3269184;                    // alias: Psel dead after scan
    float* x2g    = ws + 3334720;                    // alias

    k_trans_sel<<<dim3(128), dim3(128), 0, stream>>>(Wsel1, Ws14);
    k_init<<<dim3(NB), dim3(SS), 0, stream>>>(acts, rec);
    k_encode<<<dim3(NB * 12), dim3(256), 0, stream>>>(sent, emb, Wenc, benc, state);
    k_logits0<<<dim3(NB * 5), dim3(256), 0, stream>>>(state, Ws14, bs1, Ws2, bs2, logits);

    for (int t = 0; t < SS - 1; t++)   // t = 0..94
        k_step<<<dim3(256), dim3(640), 0, stream>>>(Wcomp, bcomp, Ws14, bs1, Ws2, bs2,
                                                    logits, acts, rec, nlUsed, Psel, state, t);

    k_mlp1<<<dim3(NB * 4), dim3(256), 0, stream>>>(state, nlUsed, Wm1, bm1, x1g);
    k_mlp2<<<dim3(NB * 8), dim3(128), 0, stream>>>(x1g, Wm2, bm2, x2g);
    k_mlp3<<<dim3(NB), dim3(256), 0, stream>>>(x2g, Wout, bout, out);
}